// Round 11
// baseline (753822.510 us; speedup 1.0000x reference)
//
#include <hip/hip_runtime.h>

#define T_DIM 256
#define B_DIM 128
#define F_DIM 1024
#define G_DIM 4096
#define LA    6
#define XWR   16

typedef short bf8   __attribute__((ext_vector_type(8)));
typedef float f32x4 __attribute__((ext_vector_type(4)));
typedef unsigned int u32x4 __attribute__((ext_vector_type(4)));
typedef unsigned long long u64;

// ---- ws layout (bytes) ----
#define OFF_CTRL 0ull
#define SZ_CTRL  131072ull
#define OFF_WIP  (SZ_CTRL)
#define SZ_WP    (8ull<<20)
#define OFF_WHP  (OFF_WIP+SZ_WP)
#define OFF_HR   (OFF_WHP+SZ_WP)
#define SZ_HR    (2ull*262144ull)
#define OFF_XW   (OFF_HR+SZ_HR)
#define SZ_XW    ((u64)XWR*1048576ull)     // 16 slots x [256 ntile][128 row][16 col] bf16
#define OFF_XPK  (OFF_XW+SZ_XW)
#define WS_MIN   OFF_XPK
#define WS_BIG   (OFF_XPK + 64ull*1048576ull)
// ctrl: cnt[g]@g*128, arrive@2048, ltag[i]@4096+i*128, btag[i]@40960+i*128
#define CO_ARR   2048
#define CO_LTAG  4096
#define CO_BTAG  40960

__device__ __forceinline__ unsigned short f2bf(float v) {
  union { float f; unsigned u; } c; c.f = v;
  return (unsigned short)((c.u + 0x7fffu + ((c.u >> 16) & 1u)) >> 16);
}
__device__ __forceinline__ float bf2f(unsigned short u) {
  union { unsigned i; float f; } c; c.i = ((unsigned)u) << 16; return c.f;
}
__device__ __forceinline__ float sigm(float x)  { return 1.f / (1.f + __expf(-x)); }
__device__ __forceinline__ float tanh_(float x) { return 1.f - 2.f / (1.f + __expf(2.f * x)); }
__device__ __forceinline__ bf8 as_bf8(u32x4 v) { union { u32x4 a; bf8 b; } u; u.a = v; return u.b; }
__device__ __forceinline__ unsigned umin2(unsigned a, unsigned b) { return a < b ? a : b; }
__device__ __forceinline__ bf8 cvt_bf8(float4 a, float4 b) {
  union { unsigned short s[8]; bf8 v; } u;
  u.s[0]=f2bf(a.x); u.s[1]=f2bf(a.y); u.s[2]=f2bf(a.z); u.s[3]=f2bf(a.w);
  u.s[4]=f2bf(b.x); u.s[5]=f2bf(b.y); u.s[6]=f2bf(b.z); u.s[7]=f2bf(b.w);
  return u.v;
}
__device__ __forceinline__ unsigned ldflag(const void* p, bool loc) {
  unsigned v;
  if (loc) asm volatile("global_load_dword %0, %1, off sc0\n\ts_waitcnt vmcnt(0)" : "=v"(v) : "v"(p));
  else     asm volatile("global_load_dword %0, %1, off sc0 sc1\n\ts_waitcnt vmcnt(0)" : "=v"(v) : "v"(p));
  return v;
}
__device__ __forceinline__ void stflag(void* p, unsigned v, bool loc) {
  if (loc) *(volatile unsigned*)p = v;
  else __hip_atomic_store((unsigned*)p, v, __ATOMIC_RELAXED, __HIP_MEMORY_SCOPE_AGENT);
}
__device__ __forceinline__ u32x4 ld16_mall(const void* p) {
  u32x4 v;
  asm volatile("global_load_dwordx4 %0, %1, off sc0 sc1\n\ts_waitcnt vmcnt(0)" : "=v"(v) : "v"(p));
  return v;
}
__device__ __forceinline__ void ld4(u32x4& a, u32x4& b, u32x4& c, u32x4& d,
                                    const void* p0, const void* p1, const void* p2, const void* p3, bool loc) {
  if (loc)
    asm volatile("global_load_dwordx4 %0, %4, off sc0\n\t"
                 "global_load_dwordx4 %1, %5, off sc0\n\t"
                 "global_load_dwordx4 %2, %6, off sc0\n\t"
                 "global_load_dwordx4 %3, %7, off sc0\n\t"
                 "s_waitcnt vmcnt(0)"
                 : "=&v"(a), "=&v"(b), "=&v"(c), "=&v"(d)
                 : "v"(p0), "v"(p1), "v"(p2), "v"(p3));
  else
    asm volatile("global_load_dwordx4 %0, %4, off sc0 sc1\n\t"
                 "global_load_dwordx4 %1, %5, off sc0 sc1\n\t"
                 "global_load_dwordx4 %2, %6, off sc0 sc1\n\t"
                 "global_load_dwordx4 %3, %7, off sc0 sc1\n\t"
                 "s_waitcnt vmcnt(0)"
                 : "=&v"(a), "=&v"(b), "=&v"(c), "=&v"(d)
                 : "v"(p0), "v"(p1), "v"(p2), "v"(p3));
}
__device__ __forceinline__ void st_dword_sc1(void* p, unsigned v) {
  asm volatile("global_store_dword %0, %1, off sc1" :: "v"(p), "v"(v) : "memory");
}

// ---- pack W -> MFMA-B frag order bf16: (nt*32+kt)*64+lane ----
__global__ __launch_bounds__(256) void pack_w(const float* __restrict__ Wi, const float* __restrict__ Wh,
                                              unsigned short* __restrict__ wip, unsigned short* __restrict__ whp) {
  int gid = blockIdx.x * 256 + threadIdx.x;
  const float* src = (gid >= 524288) ? Wh : Wi;
  unsigned short* dst = (gid >= 524288) ? whp : wip;
  int r = gid & 524287, nt = r >> 11, kt = (r >> 6) & 31, l = r & 63;
  int col = nt * 16 + (l & 15), k0 = kt * 32 + ((l >> 4) << 3);
  bf8 v8;
#pragma unroll
  for (int j = 0; j < 8; ++j) v8[j] = (short)f2bf(src[(size_t)(k0 + j) * G_DIM + col]);
  *reinterpret_cast<bf8*>(dst + (size_t)r * 8) = v8;
}

__global__ __launch_bounds__(256) void pack_h(const float* __restrict__ h0, unsigned short* __restrict__ hr) {
  int i = blockIdx.x * 256 + threadIdx.x;
  hr[i] = f2bf(h0[i]);
}

__global__ __launch_bounds__(256) void pack_x(const float* __restrict__ x, unsigned short* __restrict__ xpk) {
  int gid = blockIdx.x * 256 + threadIdx.x;
  const float4* s = reinterpret_cast<const float4*>(x + (size_t)gid * 8);
  *reinterpret_cast<bf8*>(xpk + (size_t)gid * 8) = cvt_bf8(s[0], s[1]);
}

struct SmT {
  u32x4 wi[32][64];        // 32 KB Wi ntile B-frags
  u32x4 hst[32][64];       // 32 KB h A-frags
  u32x4 xwst[8][16][2];    // 4 KB  staged xw tile [n8][row][half]
  float gates[4][16][33];  // 8.4 KB
  int   info[8];
  char  pad[17000];        // force 1 WG/CU
};

__global__ __launch_bounds__(512, 2) void lstm_scan(
    const float* __restrict__ x, const unsigned short* __restrict__ xpk, int useXpk,
    const unsigned short* __restrict__ wip, const unsigned short* __restrict__ whp,
    unsigned short* __restrict__ hring, unsigned short* __restrict__ xwring,
    const float* __restrict__ bias, const int* __restrict__ term,
    const float* __restrict__ c0, float* __restrict__ out, char* __restrict__ ctrl) {
  __shared__ SmT sm;

  const int wg = blockIdx.x, tid = threadIdx.x;
  const int wv = tid >> 6, lane = tid & 63, oct = lane >> 4;

  // ---- startup: self-organize by XCC_ID ----
  if (tid == 0) {
    unsigned xcc = __builtin_amdgcn_s_getreg(63508) & 7u;
    unsigned slot = __hip_atomic_fetch_add((unsigned*)(ctrl + (size_t)xcc * 128), 1u,
                                           __ATOMIC_RELAXED, __HIP_MEMORY_SCOPE_AGENT);
    sm.info[0] = (int)xcc; sm.info[1] = (int)slot;
    __hip_atomic_fetch_add((unsigned*)(ctrl + CO_ARR), 1u, __ATOMIC_RELEASE, __HIP_MEMORY_SCOPE_AGENT);
  }
  __syncthreads();
  if (tid == 0) {
    while (__hip_atomic_load((unsigned*)(ctrl + CO_ARR), __ATOMIC_ACQUIRE, __HIP_MEMORY_SCOPE_AGENT) < 256u)
      __builtin_amdgcn_s_sleep(8);
    int ok = 1;
    for (int g = 0; g < 8; ++g)
      ok &= (__hip_atomic_load((unsigned*)(ctrl + (size_t)g * 128), __ATOMIC_RELAXED, __HIP_MEMORY_SCOPE_AGENT) == 32u);
    sm.info[2] = ok;
  }
  __syncthreads();
  const bool loc = (sm.info[2] != 0);
  const int G = loc ? sm.info[0] : (wg >> 5);
  const int R = loc ? sm.info[1] : (wg & 31);
  char* ltagB = ctrl + CO_LTAG;
  char* btagB = ctrl + CO_BTAG;
  const int nt_bg = G * 32 + R;

  // ---- Wi ntile -> LDS ----
  {
    int jb = tid >> 6, l6 = tid & 63;
#pragma unroll
    for (int k = 0; k < 4; ++k) {
      int j = jb + 8 * k;
      sm.wi[j][l6] = *reinterpret_cast<const u32x4*>(wip + ((size_t)(nt_bg * 32 + j) * 64 + l6) * 8);
    }
  }
  // ---- Wh ntile (per wave) -> VGPRs ----
  const int gt = wv >> 1, hf = wv & 1;
  const int ntS = gt * 64 + R * 2 + hf;
  bf8 wh[32];
#pragma unroll
  for (int k = 0; k < 32; ++k)
    wh[k] = *reinterpret_cast<const bf8*>(whp + ((size_t)(ntS * 32 + k) * 64 + lane) * 8);
#pragma unroll
  for (int k = 0; k < 32; ++k) asm volatile("" : "+v"(wh[k]));
  __syncthreads();

  // ---- per-thread epilogue state ----
  const int erow = tid >> 5, ecol = tid & 31;
  const int grow = G * 16 + erow, fcol = R * 32 + ecol;
  float b4[4];
#pragma unroll
  for (int g = 0; g < 4; ++g) b4[g] = bias[g * F_DIM + fcol];
  float c_reg = c0[(size_t)grow * F_DIM + fcol];

  float* fc = out + (size_t)T_DIM * B_DIM * F_DIM;
  float* fh = fc + (size_t)B_DIM * F_DIM;
  unsigned mmin = 0;

  // ---- background xw producer: own ntile, all 128 rows ----
  auto bg_pass = [&](int s) {
    f32x4 acc = {0, 0, 0, 0};
    if (useXpk) {
      const unsigned short* xb = xpk + (size_t)s * 131072 + (size_t)(wv * 16 + (lane & 15)) * 1024 + oct * 8;
#pragma unroll
      for (int j = 0; j < 32; ++j) {
        bf8 A = *reinterpret_cast<const bf8*>(xb + j * 32);
        acc = __builtin_amdgcn_mfma_f32_16x16x32_bf16(A, as_bf8(sm.wi[j][lane]), acc, 0, 0, 0);
      }
    } else {
      const float* xb = x + (size_t)s * 131072 + (size_t)(wv * 16 + (lane & 15)) * 1024 + oct * 8;
#pragma unroll
      for (int j = 0; j < 32; ++j) {
        float4 a = *reinterpret_cast<const float4*>(xb + j * 32);
        float4 b = *reinterpret_cast<const float4*>(xb + j * 32 + 4);
        acc = __builtin_amdgcn_mfma_f32_16x16x32_bf16(cvt_bf8(a, b), as_bf8(sm.wi[j][lane]), acc, 0, 0, 0);
      }
    }
    // coalesced pair-packed stores: [slot][nt][row][16col]
    unsigned short* slotp = xwring + (size_t)(s % XWR) * 524288 + (size_t)nt_bg * 2048;
#pragma unroll
    for (int r = 0; r < 4; ++r) {
      int row = wv * 16 + oct * 4 + r;
      unsigned my = f2bf(acc[r]);
      unsigned nb = (unsigned)__shfl_xor((int)my, 1, 64);
      if (!(lane & 1)) {
        unsigned pk = my | (nb << 16);
        st_dword_sc1(slotp + row * 16 + ((lane & 15) & ~1), pk);
      }
    }
  };

  // consumer xw stage: 4 KB tile -> LDS (threads 64..319)
  auto stage_xw = [&](int s) {
    if (tid >= 64 && tid < 320) {
      int j = tid - 64;
      int n8 = j >> 5, row16 = (j >> 1) & 15, hf2 = j & 1;
      int n = (n8 >> 1) * 64 + R * 2 + (n8 & 1);
      const void* p = xwring + (size_t)(s % XWR) * 524288 + (size_t)n * 2048 +
                      (size_t)(G * 16 + row16) * 16 + hf2 * 8;
      sm.xwst[n8][row16][hf2] = ld16_mall(p);
    }
  };

  // amortized producer-progress poll (wave 0 only)
  auto poll_bt = [&](unsigned need) {
    for (;;) {
      unsigned f0 = ldflag(btagB + (size_t)lane * 128, false);
      unsigned f1 = ldflag(btagB + (size_t)(lane + 64) * 128, false);
      unsigned f2 = ldflag(btagB + (size_t)(lane + 128) * 128, false);
      unsigned f3 = ldflag(btagB + (size_t)(lane + 192) * 128, false);
      unsigned m = umin2(umin2(f0, f1), umin2(f2, f3));
      if (__all(m >= need)) {
#pragma unroll
        for (int d = 1; d < 64; d <<= 1)
          m = umin2(m, (unsigned)__shfl_xor((int)m, d, 64));
        mmin = m;
        break;
      }
      __builtin_amdgcn_s_sleep(2);
    }
  };

  // ---- warmup: produce xw[0..LA-1], certify, stage xw(0) ----
  for (int s = 0; s < LA; ++s) bg_pass(s);
  __syncthreads();
  if (tid == 0) stflag(btagB + (size_t)nt_bg * 128, (unsigned)LA, false);
  if (wv == 0) poll_bt(1u);
  __syncthreads();
  stage_xw(0);

  // ---- main scan loop ----
#pragma unroll 1
  for (int t = 0; t < T_DIM; ++t) {
    // wait own-group h(t)
    if (t > 0 && wv == 0) {
      const void* lp = ltagB + (size_t)(G * 32 + (lane & 31)) * 128;
      for (;;) {
        unsigned f = ldflag(lp, loc);
        if (__all((lane >= 32) | (f >= (unsigned)t))) break;
        __builtin_amdgcn_s_sleep(1);
      }
    }
    __syncthreads();

    // stage h(t) -> LDS A-frags (termination-masked)
    {
      int row = tid & 15, o2 = (tid >> 4) & 3, l6 = tid & 63, jb = tid >> 6;
      const unsigned short* hs = hring + (size_t)(t & 1) * 131072 + (size_t)(G * 16 + row) * 1024 + o2 * 8;
      int trm = term[t * B_DIM + G * 16 + row];
      u32x4 v0, v1, v2, v3;
      ld4(v0, v1, v2, v3, hs + jb * 32, hs + (jb + 8) * 32, hs + (jb + 16) * 32, hs + (jb + 24) * 32, loc);
      u32x4 zz = {0, 0, 0, 0};
      if (trm) { v0 = zz; v1 = zz; v2 = zz; v3 = zz; }
      sm.hst[jb][l6] = v0; sm.hst[jb + 8][l6] = v1; sm.hst[jb + 16][l6] = v2; sm.hst[jb + 24][l6] = v3;
    }
    __syncthreads();

    // h @ Wh (weights in regs)
    f32x4 acc = {0, 0, 0, 0};
#pragma unroll
    for (int j = 0; j < 32; ++j)
      acc = __builtin_amdgcn_mfma_f32_16x16x32_bf16(as_bf8(sm.hst[j][lane]), wh[j], acc, 0, 0, 0);
#pragma unroll
    for (int r = 0; r < 4; ++r) sm.gates[gt][oct * 4 + r][hf * 16 + (lane & 15)] = acc[r];
    __syncthreads();

    // epilogue (1 cell/thread), xw from LDS
    int trmE = term[t * B_DIM + grow];
    const unsigned short* xws = (const unsigned short*)&sm.xwst[0][0][0];
    float hx[4];
#pragma unroll
    for (int g = 0; g < 4; ++g)
      hx[g] = bf2f(xws[((g * 2 + (ecol >> 4)) * 16 + erow) * 16 + (ecol & 15)]) +
              b4[g] + sm.gates[g][erow][ecol];
    float cp = trmE ? 0.f : c_reg;
    float cn = sigm(hx[1]) * cp + sigm(hx[0]) * tanh_(hx[2]);
    float hn = sigm(hx[3]) * tanh_(cn);
    c_reg = cn;
    {
      unsigned my = f2bf(hn);
      unsigned nb = (unsigned)__shfl_xor((int)my, 1, 64);
      if (!(ecol & 1)) {
        unsigned pk = my | (nb << 16);
        void* dst = hring + (size_t)((t + 1) & 1) * 131072 + (size_t)grow * 1024 + (fcol & ~1);
        if (loc) *(volatile unsigned*)dst = pk;
        else __hip_atomic_store((unsigned*)dst, pk, __ATOMIC_RELAXED, __HIP_MEMORY_SCOPE_AGENT);
      }
    }
    __syncthreads();   // drain h publish
    if (tid == 0) stflag(ltagB + (size_t)(G * 32 + R) * 128, (unsigned)(t + 1), loc);

    // deferred HBM outputs
    out[((size_t)t * B_DIM + grow) * F_DIM + fcol] = hn;
    if (t == T_DIM - 1) {
      fc[(size_t)grow * F_DIM + fcol] = cn;
      fh[(size_t)grow * F_DIM + fcol] = hn;
    }

    // background production + certification
    if (t + LA < T_DIM) bg_pass(t + LA);
    __syncthreads();   // drain bg stores
    if (tid == 0 && t + LA < T_DIM)
      stflag(btagB + (size_t)nt_bg * 128, (unsigned)(t + LA + 1), false);

    // pre-stage xw(t+1)
    if (t + 1 < T_DIM) {
      if (wv == 0 && mmin < (unsigned)(t + 2)) poll_bt((unsigned)(t + 2));
      __syncthreads();   // certify before stage
      stage_xw(t + 1);
    }
  }
}

extern "C" void kernel_launch(void* const* d_in, const int* in_sizes, int n_in,
                              void* d_out, int out_size, void* d_ws, size_t ws_size,
                              hipStream_t stream) {
  const float* x    = (const float*)d_in[0];
  const int*   term = (const int*)d_in[1];
  const float* c0   = (const float*)d_in[2];
  const float* h0   = (const float*)d_in[3];
  const float* Wi   = (const float*)d_in[4];
  const float* Wh   = (const float*)d_in[5];
  const float* bias = (const float*)d_in[6];
  float* out = (float*)d_out;
  char*  ws  = (char*)d_ws;

  if (ws_size < WS_MIN) return;
  int useXpk = (ws_size >= WS_BIG) ? 1 : 0;

  char*           ctrl = ws + OFF_CTRL;
  unsigned short* wip  = (unsigned short*)(ws + OFF_WIP);
  unsigned short* whp  = (unsigned short*)(ws + OFF_WHP);
  unsigned short* hr   = (unsigned short*)(ws + OFF_HR);
  unsigned short* xw   = (unsigned short*)(ws + OFF_XW);
  unsigned short* xpk  = (unsigned short*)(ws + OFF_XPK);

  hipMemsetAsync(ctrl, 0, SZ_CTRL, stream);
  pack_w<<<dim3(4096), dim3(256), 0, stream>>>(Wi, Wh, wip, whp);
  pack_h<<<dim3(512),  dim3(256), 0, stream>>>(h0, hr);
  if (useXpk) pack_x<<<dim3(16384), dim3(256), 0, stream>>>(x, xpk);
  lstm_scan<<<dim3(256), dim3(512), 0, stream>>>(x, xpk, useXpk, wip, whp, hr, xw,
                                                 bias, term, c0, out, ctrl);
}

// Round 12
// 3100.458 us; speedup vs baseline: 243.1326x; 243.1326x over previous
//
#include <hip/hip_runtime.h>

#define T_DIM 256
#define B_DIM 128
#define F_DIM 1024
#define G_DIM 4096
#define LA    8
#define XWR   16

typedef short bf8   __attribute__((ext_vector_type(8)));
typedef float f32x4 __attribute__((ext_vector_type(4)));
typedef unsigned int u32x4 __attribute__((ext_vector_type(4)));
typedef unsigned long long u64;

// ---- ws layout (bytes) ----
#define OFF_CTRL 0ull
#define SZ_CTRL  131072ull
#define OFF_WIP  (SZ_CTRL)
#define SZ_WP    (8ull<<20)
#define OFF_WHP  (OFF_WIP+SZ_WP)
#define OFF_HR   (OFF_WHP+SZ_WP)
#define SZ_HR    (2ull*262144ull)
#define OFF_XW   (OFF_HR+SZ_HR)
#define SZ_XW    ((u64)XWR*1048576ull)   // 16 slots x [4 gate][128 row][1024 col] bf16
#define OFF_XPK  (OFF_XW+SZ_XW)
#define WS_MIN   OFF_XPK
#define WS_BIG   (OFF_XPK + 64ull*1048576ull)
// ctrl: cnt[g]@g*128, arrive@2048, ltag[i]@4096+i*128, btag[i]@40960+i*128
#define CO_ARR   2048
#define CO_LTAG  4096
#define CO_BTAG  40960

__device__ __forceinline__ unsigned short f2bf(float v) {
  union { float f; unsigned u; } c; c.f = v;
  return (unsigned short)((c.u + 0x7fffu + ((c.u >> 16) & 1u)) >> 16);
}
__device__ __forceinline__ float bf2f(unsigned short u) {
  union { unsigned i; float f; } c; c.i = ((unsigned)u) << 16; return c.f;
}
__device__ __forceinline__ float sigm(float x)  { return 1.f / (1.f + __expf(-x)); }
__device__ __forceinline__ float tanh_(float x) { return 1.f - 2.f / (1.f + __expf(2.f * x)); }
__device__ __forceinline__ bf8 as_bf8(u32x4 v) { union { u32x4 a; bf8 b; } u; u.a = v; return u.b; }
__device__ __forceinline__ bf8 cvt_bf8(float4 a, float4 b) {
  union { unsigned short s[8]; bf8 v; } u;
  u.s[0]=f2bf(a.x); u.s[1]=f2bf(a.y); u.s[2]=f2bf(a.z); u.s[3]=f2bf(a.w);
  u.s[4]=f2bf(b.x); u.s[5]=f2bf(b.y); u.s[6]=f2bf(b.z); u.s[7]=f2bf(b.w);
  return u.v;
}
__device__ __forceinline__ unsigned ldflag(const void* p, bool loc) {
  unsigned v;
  if (loc) asm volatile("global_load_dword %0, %1, off sc0\n\ts_waitcnt vmcnt(0)" : "=v"(v) : "v"(p));
  else     asm volatile("global_load_dword %0, %1, off sc0 sc1\n\ts_waitcnt vmcnt(0)" : "=v"(v) : "v"(p));
  return v;
}
__device__ __forceinline__ void stflag(void* p, unsigned v, bool loc) {
  if (loc) *(volatile unsigned*)p = v;
  else __hip_atomic_store((unsigned*)p, v, __ATOMIC_RELAXED, __HIP_MEMORY_SCOPE_AGENT);
}
__device__ __forceinline__ void ld4(u32x4& a, u32x4& b, u32x4& c, u32x4& d,
                                    const void* p0, const void* p1, const void* p2, const void* p3, bool loc) {
  if (loc)
    asm volatile("global_load_dwordx4 %0, %4, off sc0\n\t"
                 "global_load_dwordx4 %1, %5, off sc0\n\t"
                 "global_load_dwordx4 %2, %6, off sc0\n\t"
                 "global_load_dwordx4 %3, %7, off sc0\n\t"
                 "s_waitcnt vmcnt(0)"
                 : "=&v"(a), "=&v"(b), "=&v"(c), "=&v"(d)
                 : "v"(p0), "v"(p1), "v"(p2), "v"(p3));
  else
    asm volatile("global_load_dwordx4 %0, %4, off sc0 sc1\n\t"
                 "global_load_dwordx4 %1, %5, off sc0 sc1\n\t"
                 "global_load_dwordx4 %2, %6, off sc0 sc1\n\t"
                 "global_load_dwordx4 %3, %7, off sc0 sc1\n\t"
                 "s_waitcnt vmcnt(0)"
                 : "=&v"(a), "=&v"(b), "=&v"(c), "=&v"(d)
                 : "v"(p0), "v"(p1), "v"(p2), "v"(p3));
}
__device__ __forceinline__ void st_dword_sc1(void* p, unsigned v) {
  asm volatile("global_store_dword %0, %1, off sc1" :: "v"(p), "v"(v) : "memory");
}

// ---- pack W -> MFMA-B frag order bf16: (nt*32+kt)*64+lane ----
__global__ __launch_bounds__(256) void pack_w(const float* __restrict__ Wi, const float* __restrict__ Wh,
                                              unsigned short* __restrict__ wip, unsigned short* __restrict__ whp) {
  int gid = blockIdx.x * 256 + threadIdx.x;
  const float* src = (gid >= 524288) ? Wh : Wi;
  unsigned short* dst = (gid >= 524288) ? whp : wip;
  int r = gid & 524287, nt = r >> 11, kt = (r >> 6) & 31, l = r & 63;
  int col = nt * 16 + (l & 15), k0 = kt * 32 + ((l >> 4) << 3);
  bf8 v8;
#pragma unroll
  for (int j = 0; j < 8; ++j) v8[j] = (short)f2bf(src[(size_t)(k0 + j) * G_DIM + col]);
  *reinterpret_cast<bf8*>(dst + (size_t)r * 8) = v8;
}

__global__ __launch_bounds__(256) void pack_h(const float* __restrict__ h0, unsigned short* __restrict__ hr) {
  int i = blockIdx.x * 256 + threadIdx.x;
  hr[i] = f2bf(h0[i]);
}

__global__ __launch_bounds__(256) void pack_x(const float* __restrict__ x, unsigned short* __restrict__ xpk) {
  int gid = blockIdx.x * 256 + threadIdx.x;
  const float4* s = reinterpret_cast<const float4*>(x + (size_t)gid * 8);
  *reinterpret_cast<bf8*>(xpk + (size_t)gid * 8) = cvt_bf8(s[0], s[1]);
}

struct SmT {
  u32x4 wi[32][64];        // 32 KB  Wi ntile B-frags
  u32x4 hst[32][64];       // 32 KB  h A-frags
  float gates[4][16][33];  // 8.4 KB
  int   info[8];
  char  pad[20480];        // force 1 WG/CU
};

// ---- persistent scan: 256 WGs x 512 thr (8 waves); XCD-local fast path ----
__global__ __launch_bounds__(512, 2) void lstm_scan(
    const float* __restrict__ x, const unsigned short* __restrict__ xpk, int useXpk,
    const unsigned short* __restrict__ wip, const unsigned short* __restrict__ whp,
    unsigned short* __restrict__ hring, unsigned short* __restrict__ xwring,
    const float* __restrict__ bias, const int* __restrict__ term,
    const float* __restrict__ c0, float* __restrict__ out, char* __restrict__ ctrl) {
  __shared__ SmT sm;

  const int wg = blockIdx.x, tid = threadIdx.x;
  const int wv = tid >> 6, lane = tid & 63, oct = lane >> 4;

  // ---- startup: self-organize by XCC_ID, verdict ----
  if (tid == 0) {
    unsigned xcc = __builtin_amdgcn_s_getreg(63508) & 7u;   // hwreg(HW_REG_XCC_ID)
    unsigned slot = __hip_atomic_fetch_add((unsigned*)(ctrl + (size_t)xcc * 128), 1u,
                                           __ATOMIC_RELAXED, __HIP_MEMORY_SCOPE_AGENT);
    sm.info[0] = (int)xcc; sm.info[1] = (int)slot;
    __hip_atomic_fetch_add((unsigned*)(ctrl + CO_ARR), 1u, __ATOMIC_RELEASE, __HIP_MEMORY_SCOPE_AGENT);
  }
  __syncthreads();
  if (tid == 0) {
    while (__hip_atomic_load((unsigned*)(ctrl + CO_ARR), __ATOMIC_ACQUIRE, __HIP_MEMORY_SCOPE_AGENT) < 256u)
      __builtin_amdgcn_s_sleep(8);
    int ok = 1;
    for (int g = 0; g < 8; ++g)
      ok &= (__hip_atomic_load((unsigned*)(ctrl + (size_t)g * 128), __ATOMIC_RELAXED, __HIP_MEMORY_SCOPE_AGENT) == 32u);
    sm.info[2] = ok;
  }
  __syncthreads();
  const bool loc = (sm.info[2] != 0);
  const int G = loc ? sm.info[0] : (wg >> 5);
  const int R = loc ? sm.info[1] : (wg & 31);
  char* ltag = ctrl + CO_LTAG;
  char* btag = ctrl + CO_BTAG;

  // ---- load Wi ntile (G*32+R) into LDS; Wh ntile (per wave) into VGPRs ----
  const int nt_bg = G * 32 + R;
  {
    int jb = tid >> 6, l6 = tid & 63;
#pragma unroll
    for (int k = 0; k < 4; ++k) {
      int j = jb + 8 * k;
      sm.wi[j][l6] = *reinterpret_cast<const u32x4*>(wip + ((size_t)(nt_bg * 32 + j) * 64 + l6) * 8);
    }
  }
  const int gt = wv >> 1, hf = wv & 1;
  const int ntS = gt * 64 + R * 2 + hf;
  bf8 wh[32];
#pragma unroll
  for (int k = 0; k < 32; ++k)
    wh[k] = *reinterpret_cast<const bf8*>(whp + ((size_t)(ntS * 32 + k) * 64 + lane) * 8);
#pragma unroll
  for (int k = 0; k < 32; ++k) asm volatile("" : "+v"(wh[k]));   // pin in VGPRs
  __syncthreads();

  // ---- per-thread epilogue state ----
  const int erow = tid >> 5, ecol = tid & 31;
  const int grow = G * 16 + erow, fcol = R * 32 + ecol;
  float b4[4];
#pragma unroll
  for (int g = 0; g < 4; ++g) b4[g] = bias[g * F_DIM + fcol];
  float c_reg = c0[(size_t)grow * F_DIM + fcol];

  const int g_bg = nt_bg >> 6, cb_bg = (nt_bg & 63) * 16;
  float* fc = out + (size_t)T_DIM * B_DIM * F_DIM;
  float* fh = fc + (size_t)B_DIM * F_DIM;

  // ---- background xw producer: own ntile, all 128 rows; coalesced stores ----
  // ring layout: [slot][gate 4][row 128][col 1024] bf16
  auto bg_pass = [&](int s) {
    f32x4 acc = {0, 0, 0, 0};
    if (useXpk) {
      const unsigned short* xb = xpk + (size_t)s * 131072 + (size_t)(wv * 16 + (lane & 15)) * 1024 + oct * 8;
#pragma unroll
      for (int j = 0; j < 32; ++j) {
        bf8 A = *reinterpret_cast<const bf8*>(xb + j * 32);
        acc = __builtin_amdgcn_mfma_f32_16x16x32_bf16(A, as_bf8(sm.wi[j][lane]), acc, 0, 0, 0);
      }
    } else {
      const float* xb = x + (size_t)s * 131072 + (size_t)(wv * 16 + (lane & 15)) * 1024 + oct * 8;
#pragma unroll
      for (int j = 0; j < 32; ++j) {
        float4 a = *reinterpret_cast<const float4*>(xb + j * 32);
        float4 b = *reinterpret_cast<const float4*>(xb + j * 32 + 4);
        acc = __builtin_amdgcn_mfma_f32_16x16x32_bf16(cvt_bf8(a, b), as_bf8(sm.wi[j][lane]), acc, 0, 0, 0);
      }
    }
    unsigned short* slotp = xwring + (size_t)(s % XWR) * 524288 + (size_t)g_bg * 131072;
#pragma unroll
    for (int r = 0; r < 4; ++r) {
      int row = wv * 16 + oct * 4 + r;
      unsigned my = f2bf(acc[r]);
      unsigned nb = (unsigned)__shfl_xor((int)my, 1, 64);
      if (!(lane & 1)) {
        unsigned pk = my | (nb << 16);
        st_dword_sc1(slotp + (size_t)row * 1024 + cb_bg + ((lane & 15) & ~1), pk);
      }
    }
  };

  // ---- warmup: produce xw[0..LA-1] ----
  for (int s = 0; s < LA; ++s) bg_pass(s);
  __syncthreads();
  if (tid == 0) stflag(btag + (size_t)nt_bg * 128, 1u, false);

  // ---- main scan loop ----
#pragma unroll 1
  for (int t = 0; t < T_DIM; ++t) {
    if (wv == 0) {
      unsigned tg = (t >= LA - 1) ? (unsigned)(t - LA + 2) : 1u;   // xw/bg lag check
      for (;;) {
        unsigned f0 = ldflag(btag + (size_t)lane * 128, false);
        unsigned f1 = ldflag(btag + (size_t)(lane + 64) * 128, false);
        unsigned f2 = ldflag(btag + (size_t)(lane + 128) * 128, false);
        unsigned f3 = ldflag(btag + (size_t)(lane + 192) * 128, false);
        if (__all((f0 >= tg) & (f1 >= tg) & (f2 >= tg) & (f3 >= tg))) break;
        __builtin_amdgcn_s_sleep(2);
      }
      if (t > 0) {                                                  // own-group h(t) ready
        const void* lp = ltag + (size_t)(G * 32 + (lane & 31)) * 128;
        for (;;) {
          unsigned f = ldflag(lp, loc);
          if (__all((lane >= 32) | (f >= (unsigned)(t + 1)))) break;
          __builtin_amdgcn_s_sleep(1);
        }
      }
    }
    __syncthreads();

    // deferred btag certification: last step's bg stores are drained by the
    // barrier above (per-wave vmcnt(0) at __syncthreads)
    if (tid == 0 && t >= 1 && (t - 1 + LA) < T_DIM)
      stflag(btag + (size_t)nt_bg * 128, (unsigned)(t + 1), false);

    // xw[t] prefetch: 4 coalesced dword MALL loads (one per gate)
    unsigned xg[4];
    {
      const unsigned short* xwb = xwring + (size_t)(t % XWR) * 524288 + (size_t)grow * 1024 + (fcol & ~1);
#pragma unroll
      for (int g = 0; g < 4; ++g)
        xg[g] = __hip_atomic_load(reinterpret_cast<const unsigned*>(xwb + (size_t)g * 131072),
                                  __ATOMIC_RELAXED, __HIP_MEMORY_SCOPE_AGENT);
    }

    // stage h(t) -> LDS A-frags (termination-masked)
    {
      int row = tid & 15, o2 = (tid >> 4) & 3, l6 = tid & 63, jb = tid >> 6;
      const unsigned short* hs = hring + (size_t)(t & 1) * 131072 + (size_t)(G * 16 + row) * 1024 + o2 * 8;
      int trm = term[t * B_DIM + G * 16 + row];
      u32x4 v0, v1, v2, v3;
      ld4(v0, v1, v2, v3, hs + (jb) * 32, hs + (jb + 8) * 32, hs + (jb + 16) * 32, hs + (jb + 24) * 32, loc);
      u32x4 zz = {0, 0, 0, 0};
      if (trm) { v0 = zz; v1 = zz; v2 = zz; v3 = zz; }
      sm.hst[jb][l6] = v0; sm.hst[jb + 8][l6] = v1; sm.hst[jb + 16][l6] = v2; sm.hst[jb + 24][l6] = v3;
    }
    __syncthreads();

    // h @ Wh (weights in VGPRs)
    f32x4 acc = {0, 0, 0, 0};
#pragma unroll
    for (int j = 0; j < 32; ++j)
      acc = __builtin_amdgcn_mfma_f32_16x16x32_bf16(as_bf8(sm.hst[j][lane]), wh[j], acc, 0, 0, 0);
#pragma unroll
    for (int r = 0; r < 4; ++r) sm.gates[gt][oct * 4 + r][hf * 16 + (lane & 15)] = acc[r];
    __syncthreads();

    // epilogue (1 cell/thread) + publish h(t+1)
    int trmE = term[t * B_DIM + grow];
    float hx[4];
#pragma unroll
    for (int g = 0; g < 4; ++g)
      hx[g] = bf2f((unsigned short)(xg[g] >> ((fcol & 1) * 16))) + b4[g] + sm.gates[g][erow][ecol];
    float cp = trmE ? 0.f : c_reg;
    float cn = sigm(hx[1]) * cp + sigm(hx[0]) * tanh_(hx[2]);
    float hn = sigm(hx[3]) * tanh_(cn);
    c_reg = cn;
    {
      unsigned my = f2bf(hn);
      unsigned nb = (unsigned)__shfl_xor((int)my, 1, 64);
      if (!(ecol & 1)) {
        unsigned pk = my | (nb << 16);
        void* dst = hring + (size_t)((t + 1) & 1) * 131072 + (size_t)grow * 1024 + (fcol & ~1);
        if (loc) *(volatile unsigned*)dst = pk;
        else __hip_atomic_store((unsigned*)dst, pk, __ATOMIC_RELAXED, __HIP_MEMORY_SCOPE_AGENT);
      }
    }
    __syncthreads();                                   // drain publishes
    if (tid == 0) stflag(ltag + (size_t)(G * 32 + R) * 128, (unsigned)(t + 2), loc);

    // deferred HBM outputs
    out[((size_t)t * B_DIM + grow) * F_DIM + fcol] = hn;
    if (t == T_DIM - 1) {
      fc[(size_t)grow * F_DIM + fcol] = cn;
      fh[(size_t)grow * F_DIM + fcol] = hn;
    }

    // background xw(t+LA); stores drain at NEXT step's top barrier, certified there
    if (t + LA < T_DIM) bg_pass(t + LA);
  }
}

extern "C" void kernel_launch(void* const* d_in, const int* in_sizes, int n_in,
                              void* d_out, int out_size, void* d_ws, size_t ws_size,
                              hipStream_t stream) {
  const float* x    = (const float*)d_in[0];
  const int*   term = (const int*)d_in[1];
  const float* c0   = (const float*)d_in[2];
  const float* h0   = (const float*)d_in[3];
  const float* Wi   = (const float*)d_in[4];
  const float* Wh   = (const float*)d_in[5];
  const float* bias = (const float*)d_in[6];
  float* out = (float*)d_out;
  char*  ws  = (char*)d_ws;

  if (ws_size < WS_MIN) return;
  int useXpk = (ws_size >= WS_BIG) ? 1 : 0;

  char*           ctrl = ws + OFF_CTRL;
  unsigned short* wip  = (unsigned short*)(ws + OFF_WIP);
  unsigned short* whp  = (unsigned short*)(ws + OFF_WHP);
  unsigned short* hr   = (unsigned short*)(ws + OFF_HR);
  unsigned short* xw   = (unsigned short*)(ws + OFF_XW);
  unsigned short* xpk  = (unsigned short*)(ws + OFF_XPK);

  hipMemsetAsync(ctrl, 0, SZ_CTRL, stream);
  pack_w<<<dim3(4096), dim3(256), 0, stream>>>(Wi, Wh, wip, whp);
  pack_h<<<dim3(512),  dim3(256), 0, stream>>>(h0, hr);
  if (useXpk) pack_x<<<dim3(16384), dim3(256), 0, stream>>>(x, xpk);
  lstm_scan<<<dim3(256), dim3(512), 0, stream>>>(x, xpk, useXpk, wip, whp, hr, xw,
                                                 bias, term, c0, out, ctrl);
}